// Round 4
// baseline (182.637 us; speedup 1.0000x reference)
//
#include <hip/hip_runtime.h>
#include <hip/hip_bf16.h>

#define N_SRC 50000
#define N_DST 50000
#define N_EDGES 600000
#define IN_FEAT 128
#define OUT_FEAT 128
#define CAP 64                          // per-dst bucket capacity (Poisson(12), P(deg>64)~1e-30)

typedef __attribute__((ext_vector_type(8))) short short8;   // 8 bf16 = 4 VGPRs
typedef __attribute__((ext_vector_type(4))) float float4v;  // MFMA C/D
typedef __attribute__((ext_vector_type(4))) float f32x4;
typedef __attribute__((ext_vector_type(4))) unsigned short ushort4v;

#define FILL_BLOCKS ((N_EDGES + 255) / 256)   // 2344
#define HS4 (N_SRC * IN_FEAT / 4)             // 1,600,000 float4s per matrix
#define CVT_BLOCKS (HS4 / 256)                // 6250
#define W_BLOCKS 16                           // 4096 8-elem chunks / 256
#define K1_GRID (FILL_BLOCKS + 2 * CVT_BLOCKS + W_BLOCKS)

// ---------------------------------------------------------------------------
// K1 (split-grid fusion; fill FIRST so its atomic stream starts immediately):
//   [0, FILL)            bucket-fill: p=atomicAdd(deg[d]); permu[d*CAP+p]=src
//   [FILL, +2*CVT)       f32->bf16 convert h_s->hsb, h_d->hdb
//   [.., +16)            W f32 -> fragment-major bf16 wfrag
// R3 learning: K1 is transaction-bound (1.9 TB/s, VALU 2%), not BW-bound.
// This round: perm stores are ALSO nontemporal — skip the per-XCD L2
// write-allocate RMW; partial-line writes from all 8 XCDs coalesce at the
// shared memory side instead. Tests scattered-store-throughput theory.
// ---------------------------------------------------------------------------
__global__ __launch_bounds__(256) void fill_cvt_kernel(
    const float* __restrict__ h_s, const float* __restrict__ h_d,
    const float* __restrict__ W,
    const int* __restrict__ src, const int* __restrict__ dst,
    int* __restrict__ deg, ushort* __restrict__ permu,
    ushort* __restrict__ hsb, ushort* __restrict__ hdb,
    ushort* __restrict__ wfrag)
{
    int bid = blockIdx.x;
    int tid = threadIdx.x;

    if (bid < FILL_BLOCKS) {
        int e = bid * 256 + tid;
        if (e < N_EDGES) {
            int s = __builtin_nontemporal_load(src + e);
            int d = __builtin_nontemporal_load(dst + e);
            int p = atomicAdd(&deg[d], 1);
            if (p < CAP)
                __builtin_nontemporal_store((ushort)s, permu + (size_t)d * CAP + p);
        }
        return;
    }
    bid -= FILL_BLOCKS;

    if (bid < 2 * CVT_BLOCKS) {
        bool first = (bid < CVT_BLOCKS);
        const float* in = first ? h_s : h_d;
        ushort* outp    = first ? hsb : hdb;
        int idx = (first ? bid : bid - CVT_BLOCKS) * 256 + tid;
        f32x4 v = __builtin_nontemporal_load((const f32x4*)in + idx);
        __hip_bfloat16 o[4];
        o[0] = __float2bfloat16(v.x);
        o[1] = __float2bfloat16(v.y);
        o[2] = __float2bfloat16(v.z);
        o[3] = __float2bfloat16(v.w);
        __builtin_nontemporal_store(*(ushort4v*)o, (ushort4v*)(outp + (size_t)idx * 4));
        return;
    }
    bid -= 2 * CVT_BLOCKS;

    // ---- W convert to fragment-major bf16 (exact layout the GEMM reads):
    // chunk c: f=c>>6 (=ks*8+nt), l=c&63; elem = W[nt*16+(l&15)][ks*32+(l>>4)*8 ..+8]
    int c = bid * 256 + tid;              // [0, 4096)
    int f  = c >> 6;
    int l  = c & 63;
    int ks = f >> 3;
    int nt = f & 7;
    int row = nt * 16 + (l & 15);
    int col = ks * 32 + (l >> 4) * 8;
    const float* wp = W + (size_t)row * 256 + col;
    f32x4 w0 = __builtin_nontemporal_load((const f32x4*)wp);
    f32x4 w1 = __builtin_nontemporal_load((const f32x4*)wp + 1);
    __hip_bfloat16 o[8];
    o[0] = __float2bfloat16(w0.x); o[1] = __float2bfloat16(w0.y);
    o[2] = __float2bfloat16(w0.z); o[3] = __float2bfloat16(w0.w);
    o[4] = __float2bfloat16(w1.x); o[5] = __float2bfloat16(w1.y);
    o[6] = __float2bfloat16(w1.z); o[7] = __float2bfloat16(w1.w);
    __builtin_nontemporal_store(*(short8*)o, (short8*)(wfrag + (size_t)c * 8));
}

// ---------------------------------------------------------------------------
// K2: gather-mean, one wave per dst row (12500 blocks -> max TLP).
// ONE dependent memory round for 99.95% of rows: preload 24 slot ids
// (uniform scalar loads), wave-uniform branch into an 8/16/24-wide single
// flight of independent row reads. Masked slots read row 0 (broadcast, L1).
// Tail loop only for deg>24 (P ~ 5e-4).
// ---------------------------------------------------------------------------
template<int NB>
__device__ inline void gather_batch(const ushort2* __restrict__ hp,
                                    const int* t, int dgr, int lane,
                                    float& ax, float& ay)
{
    ushort2 u[NB];
#pragma unroll
    for (int q = 0; q < NB; ++q) {
        int s = (q < dgr) ? t[q] : 0;
        u[q] = hp[(size_t)s * 64 + lane];
    }
#pragma unroll
    for (int q = 0; q < NB; ++q) {
        float m = (q < dgr) ? 1.f : 0.f;
        ax += m * __uint_as_float((unsigned)u[q].x << 16);
        ay += m * __uint_as_float((unsigned)u[q].y << 16);
    }
}

__global__ __launch_bounds__(256) void gather_kernel(
    const ushort* __restrict__ hsb, const int* __restrict__ deg,
    const ushort* __restrict__ permu, ushort* __restrict__ neighb)
{
    int wave = threadIdx.x >> 6;
    int lane = threadIdx.x & 63;
    int row  = blockIdx.x * 4 + wave;
    if (row >= N_DST) return;

    int dg  = deg[row];
    int dgr = (dg < CAP) ? dg : CAP;
    const ushort* prow = permu + (size_t)row * CAP;
    const ushort2* hp  = (const ushort2*)hsb;

    // preload first 24 slot ids (uniform -> scalar loads)
    ushort4 p[6];
#pragma unroll
    for (int i = 0; i < 6; ++i) p[i] = *(const ushort4*)(prow + i * 4);
    int t[24];
#pragma unroll
    for (int i = 0; i < 6; ++i) {
        t[i * 4 + 0] = p[i].x; t[i * 4 + 1] = p[i].y;
        t[i * 4 + 2] = p[i].z; t[i * 4 + 3] = p[i].w;
    }

    float ax = 0.f, ay = 0.f;
    if (dgr <= 8) {
        gather_batch<8>(hp, t, dgr, lane, ax, ay);
    } else if (dgr <= 16) {
        gather_batch<16>(hp, t, dgr, lane, ax, ay);
    } else {
        gather_batch<24>(hp, t, dgr, lane, ax, ay);
        for (int j = 24; j < dgr; j += 8) {          // P(deg>24) ~ 5e-4
            ushort4 pa = *(const ushort4*)(prow + j);
            ushort4 pb = *(const ushort4*)(prow + j + 4);
            int tt[8] = {pa.x, pa.y, pa.z, pa.w, pb.x, pb.y, pb.z, pb.w};
            ushort2 u[8];
#pragma unroll
            for (int q = 0; q < 8; ++q) {
                int s = (j + q < dgr) ? tt[q] : 0;
                u[q] = hp[(size_t)s * 64 + lane];
            }
#pragma unroll
            for (int q = 0; q < 8; ++q) {
                float m = (j + q < dgr) ? 1.f : 0.f;
                ax += m * __uint_as_float((unsigned)u[q].x << 16);
                ay += m * __uint_as_float((unsigned)u[q].y << 16);
            }
        }
    }

    float inv = (dg > 0) ? (1.0f / (float)dg) : 0.0f;
    __hip_bfloat16 ox = __float2bfloat16(ax * inv);
    __hip_bfloat16 oy = __float2bfloat16(ay * inv);
    unsigned pk = (unsigned)*(ushort*)&ox | ((unsigned)*(ushort*)&oy << 16);
    __builtin_nontemporal_store(pk, (unsigned*)(neighb + (size_t)row * IN_FEAT) + lane);
}

// ---------------------------------------------------------------------------
// K3: MFMA bf16 GEMM, zero LDS, zero syncthreads, 64 rows/block:
//   out = [hdb | neighb] @ wfrag.T + b      (782 blocks x 4 waves)
// Each wave: 16 rows x 128 cols = 1 m-frag x 8 n-frags, 64 MFMAs.
// B-frags stream from the 64 KB L2-hot wfrag; A/out are single-use ->
// nontemporal, keeping wfrag resident.
// ---------------------------------------------------------------------------
__global__ __launch_bounds__(256) void gemm_mfma_kernel(
    const ushort* __restrict__ hdb, const ushort* __restrict__ neighb,
    const ushort* __restrict__ wfrag, const float* __restrict__ b,
    float* __restrict__ out)
{
    int tid  = threadIdx.x;
    int wave = tid >> 6;
    int lane = tid & 63;
    int lm   = lane & 15;
    int lq   = lane >> 4;

    int row0 = blockIdx.x * 64 + wave * 16;
    int ar   = row0 + lm;  ar = (ar < N_DST) ? ar : (N_DST - 1);
    const ushort* ah = hdb    + (size_t)ar * IN_FEAT + lq * 8;
    const ushort* an = neighb + (size_t)ar * IN_FEAT + lq * 8;

    float4v acc[8];
#pragma unroll
    for (int nt = 0; nt < 8; ++nt) acc[nt] = (float4v){0.f, 0.f, 0.f, 0.f};

#pragma unroll
    for (int ks = 0; ks < 8; ++ks) {
        int koff = (ks & 3) * 32;
        short8 af = (ks < 4)
            ? __builtin_nontemporal_load((const short8*)(ah + koff))
            : __builtin_nontemporal_load((const short8*)(an + koff));
#pragma unroll
        for (int nt = 0; nt < 8; ++nt) {
            short8 bf = *(const short8*)(wfrag + ((size_t)(ks * 8 + nt) * 64 + lane) * 8);
            acc[nt] = __builtin_amdgcn_mfma_f32_16x16x32_bf16(af, bf, acc[nt], 0, 0, 0);
        }
    }

    // ---- epilogue: C/D layout col=lane&15, row=(lane>>4)*4+reg ----
    int orow0 = row0 + lq * 4;
#pragma unroll
    for (int nt = 0; nt < 8; ++nt) {
        int col = nt * 16 + lm;
        float bias = b[col];
#pragma unroll
        for (int r = 0; r < 4; ++r) {
            int o = orow0 + r;
            if (o < N_DST)
                __builtin_nontemporal_store(acc[nt][r] + bias,
                                            out + (size_t)o * OUT_FEAT + col);
        }
    }
}

extern "C" void kernel_launch(void* const* d_in, const int* in_sizes, int n_in,
                              void* d_out, int out_size, void* d_ws, size_t ws_size,
                              hipStream_t stream) {
    const float* h_s = (const float*)d_in[0];
    const float* h_d = (const float*)d_in[1];
    const int*   src = (const int*)d_in[2];
    const int*   dst = (const int*)d_in[3];
    const float* W   = (const float*)d_in[4];
    const float* b   = (const float*)d_in[5];
    float* out = (float*)d_out;

    // workspace layout (~45 MB), all 16-B aligned:
    //   deg    int[50000]            @ 0          (200,000 B)
    //   permu  ushort[50000*64]      @ 200,000    (6,400,000 B)
    //   hsb    ushort[50000*128]     @ 6,600,000  (12,800,000 B)
    //   hdb    ushort[50000*128]     @ 19,400,000 (12,800,000 B)
    //   neighb ushort[50000*128]     @ 32,200,000 (12,800,000 B)
    //   wfrag  ushort[32768]         @ 45,000,000 (65,536 B)
    char* ws = (char*)d_ws;
    int*    deg    = (int*)ws;
    ushort* permu  = (ushort*)(ws + 200000);
    ushort* hsb    = (ushort*)(ws + 6600000);
    ushort* hdb    = (ushort*)(ws + 19400000);
    ushort* neighb = (ushort*)(ws + 32200000);
    ushort* wfrag  = (ushort*)(ws + 45000000);

    hipMemsetAsync(deg, 0, N_DST * sizeof(int), stream);

    fill_cvt_kernel<<<K1_GRID, 256, 0, stream>>>(
        h_s, h_d, W, src, dst, deg, permu, hsb, hdb, wfrag);
    gather_kernel<<<(N_DST + 3) / 4, 256, 0, stream>>>(
        hsb, deg, permu, neighb);
    gemm_mfma_kernel<<<(N_DST + 63) / 64, 256, 0, stream>>>(
        hdb, neighb, wfrag, b, out);
}

// Round 5
// 176.701 us; speedup vs baseline: 1.0336x; 1.0336x over previous
//
#include <hip/hip_runtime.h>
#include <hip/hip_bf16.h>

#define N_SRC 50000
#define N_DST 50000
#define N_EDGES 600000
#define IN_FEAT 128
#define OUT_FEAT 128
#define CAP 64                          // per-dst bucket capacity (Poisson(12), P(deg>64)~1e-30)

typedef __attribute__((ext_vector_type(8))) short short8;   // 8 bf16 = 4 VGPRs
typedef __attribute__((ext_vector_type(4))) float float4v;  // MFMA C/D
typedef __attribute__((ext_vector_type(4))) float f32x4;
typedef __attribute__((ext_vector_type(4))) unsigned short ushort4v;

#define FILL_BLOCKS ((N_EDGES + 255) / 256)   // 2344
#define HS4 (N_SRC * IN_FEAT / 4)             // 1,600,000 float4s per matrix
#define CVT_BLOCKS (HS4 / 256)                // 6250
#define W_BLOCKS 16                           // 4096 8-elem chunks / 256
#define K1_GRID (FILL_BLOCKS + 2 * CVT_BLOCKS + W_BLOCKS)

// ---------------------------------------------------------------------------
// K1 — EXACT round-3 form (best measured 46.1 µs). R4's nt perm store
// regressed (50 µs): the fill wall is atomic+scatter transaction throughput,
// not write-allocate. Cached perm store, nt everything streaming.
// ---------------------------------------------------------------------------
__global__ __launch_bounds__(256) void fill_cvt_kernel(
    const float* __restrict__ h_s, const float* __restrict__ h_d,
    const float* __restrict__ W,
    const int* __restrict__ src, const int* __restrict__ dst,
    int* __restrict__ deg, ushort* __restrict__ permu,
    ushort* __restrict__ hsb, ushort* __restrict__ hdb,
    ushort* __restrict__ wfrag)
{
    int bid = blockIdx.x;
    int tid = threadIdx.x;

    if (bid < FILL_BLOCKS) {
        int e = bid * 256 + tid;
        if (e < N_EDGES) {
            int s = __builtin_nontemporal_load(src + e);
            int d = __builtin_nontemporal_load(dst + e);
            int p = atomicAdd(&deg[d], 1);
            if (p < CAP) permu[(size_t)d * CAP + p] = (ushort)s;
        }
        return;
    }
    bid -= FILL_BLOCKS;

    if (bid < 2 * CVT_BLOCKS) {
        bool first = (bid < CVT_BLOCKS);
        const float* in = first ? h_s : h_d;
        ushort* outp    = first ? hsb : hdb;
        int idx = (first ? bid : bid - CVT_BLOCKS) * 256 + tid;
        f32x4 v = __builtin_nontemporal_load((const f32x4*)in + idx);
        __hip_bfloat16 o[4];
        o[0] = __float2bfloat16(v.x);
        o[1] = __float2bfloat16(v.y);
        o[2] = __float2bfloat16(v.z);
        o[3] = __float2bfloat16(v.w);
        __builtin_nontemporal_store(*(ushort4v*)o, (ushort4v*)(outp + (size_t)idx * 4));
        return;
    }
    bid -= 2 * CVT_BLOCKS;

    // ---- W convert to fragment-major bf16 (exact layout the GEMM reads):
    // chunk c: f=c>>6 (=ks*8+nt), l=c&63; elem = W[nt*16+(l&15)][ks*32+(l>>4)*8 ..+8]
    int c = bid * 256 + tid;              // [0, 4096)
    int f  = c >> 6;
    int l  = c & 63;
    int ks = f >> 3;
    int nt = f & 7;
    int row = nt * 16 + (l & 15);
    int col = ks * 32 + (l >> 4) * 8;
    const float* wp = W + (size_t)row * 256 + col;
    f32x4 w0 = __builtin_nontemporal_load((const f32x4*)wp);
    f32x4 w1 = __builtin_nontemporal_load((const f32x4*)wp + 1);
    __hip_bfloat16 o[8];
    o[0] = __float2bfloat16(w0.x); o[1] = __float2bfloat16(w0.y);
    o[2] = __float2bfloat16(w0.z); o[3] = __float2bfloat16(w0.w);
    o[4] = __float2bfloat16(w1.x); o[5] = __float2bfloat16(w1.y);
    o[6] = __float2bfloat16(w1.z); o[7] = __float2bfloat16(w1.w);
    __builtin_nontemporal_store(*(short8*)o, (short8*)(wfrag + (size_t)c * 8));
}

// ---------------------------------------------------------------------------
// K2 (fused gather-mean + MFMA GEMM with TLP — fixes round-2's failure):
// 16 dst rows per 256-thr block -> 3125 blocks (12/CU), 4 gather rows/wave,
// 4 KB LDS. Eliminates neighb HBM round-trip + the K3 launch entirely.
// Phase A: each wave gather-means 4 rows into XOR-swizzled LDS tile
//          (byte ^= (row&7)<<4; ds_read_b128-conflict-free enough, r2 data).
// Phase B: out[16x128] = [hdb_rows | sM] @ wfrag.T + b; wave w does
//          nt in {2w, 2w+1} (2 n-frags x 8 ks = 16 MFMAs/wave).
// 50000 = 3125*16 exactly -> no bounds checks.
// ---------------------------------------------------------------------------
__global__ __launch_bounds__(256) void gather_gemm_kernel(
    const ushort* __restrict__ hsb, const int* __restrict__ deg,
    const ushort* __restrict__ permu, const ushort* __restrict__ hdb,
    const ushort* __restrict__ wfrag, const float* __restrict__ b,
    float* __restrict__ out)
{
    __shared__ ushort sM[16 * 128];   // 4 KB mean tile (swizzled)

    int tid  = threadIdx.x;
    int wave = tid >> 6;
    int lane = tid & 63;
    int lm   = lane & 15;
    int lq   = lane >> 4;
    int row0 = blockIdx.x * 16;

    // ---- Phase A: gather-mean 4 rows per wave ----
    for (int r = 0; r < 4; ++r) {
        int lr  = wave * 4 + r;
        int row = row0 + lr;
        int dg  = deg[row];
        int dgr = (dg < CAP) ? dg : CAP;
        const ushort* prow = permu + (size_t)row * CAP;
        const ushort2* hp  = (const ushort2*)hsb;

        ushort4 p0 = *(const ushort4*)(prow);
        ushort4 p1 = *(const ushort4*)(prow + 4);
        ushort4 p2 = *(const ushort4*)(prow + 8);
        ushort4 p3 = *(const ushort4*)(prow + 12);
        int t[16] = {p0.x, p0.y, p0.z, p0.w, p1.x, p1.y, p1.z, p1.w,
                     p2.x, p2.y, p2.z, p2.w, p3.x, p3.y, p3.z, p3.w};

        float ax = 0.f, ay = 0.f;
        ushort2 u[16];
#pragma unroll
        for (int q = 0; q < 16; ++q) {
            int s = (q < dgr) ? t[q] : 0;
            u[q] = hp[(size_t)s * 64 + lane];
        }
#pragma unroll
        for (int q = 0; q < 16; ++q) {
            float m = (q < dgr) ? 1.f : 0.f;
            ax += m * __uint_as_float((unsigned)u[q].x << 16);
            ay += m * __uint_as_float((unsigned)u[q].y << 16);
        }
        for (int j = 16; j < dgr; j += 8) {          // P(deg>16)~11%
            ushort4 pa = *(const ushort4*)(prow + j);
            ushort4 pb = *(const ushort4*)(prow + j + 4);
            int tt[8] = {pa.x, pa.y, pa.z, pa.w, pb.x, pb.y, pb.z, pb.w};
            ushort2 v[8];
#pragma unroll
            for (int q = 0; q < 8; ++q) {
                int s = (j + q < dgr) ? tt[q] : 0;
                v[q] = hp[(size_t)s * 64 + lane];
            }
#pragma unroll
            for (int q = 0; q < 8; ++q) {
                float m = (j + q < dgr) ? 1.f : 0.f;
                ax += m * __uint_as_float((unsigned)v[q].x << 16);
                ay += m * __uint_as_float((unsigned)v[q].y << 16);
            }
        }

        float inv = (dg > 0) ? (1.0f / (float)dg) : 0.0f;
        __hip_bfloat16 ox = __float2bfloat16(ax * inv);
        __hip_bfloat16 oy = __float2bfloat16(ay * inv);
        unsigned pk = (unsigned)*(ushort*)&ox | ((unsigned)*(ushort*)&oy << 16);
        unsigned byte = ((unsigned)(lr * 256 + lane * 4)) ^ (((unsigned)lr & 7u) << 4);
        *(unsigned*)((char*)sM + byte) = pk;
    }
    __syncthreads();

    // ---- Phase B: 16x128 MFMA tile; wave covers cols [wave*32, +32) ----
    const ushort* ah = hdb + (size_t)(row0 + lm) * IN_FEAT + lq * 8;

    float4v acc[2];
    acc[0] = (float4v){0.f, 0.f, 0.f, 0.f};
    acc[1] = (float4v){0.f, 0.f, 0.f, 0.f};

#pragma unroll
    for (int ks = 0; ks < 8; ++ks) {
        short8 af;
        if (ks < 4) {
            af = __builtin_nontemporal_load((const short8*)(ah + ks * 32));
        } else {
            unsigned byte = ((unsigned)(lm * 256 + (((ks - 4) * 32 + lq * 8) * 2)))
                            ^ (((unsigned)lm & 7u) << 4);
            af = *(const short8*)((char*)sM + byte);
        }
#pragma unroll
        for (int j = 0; j < 2; ++j) {
            int nt = wave * 2 + j;
            short8 bf = *(const short8*)(wfrag + ((size_t)(ks * 8 + nt) * 64 + lane) * 8);
            acc[j] = __builtin_amdgcn_mfma_f32_16x16x32_bf16(af, bf, acc[j], 0, 0, 0);
        }
    }

    // ---- epilogue: C/D layout col=lane&15, row=(lane>>4)*4+reg ----
#pragma unroll
    for (int j = 0; j < 2; ++j) {
        int nt  = wave * 2 + j;
        int col = nt * 16 + lm;
        float bias = b[col];
#pragma unroll
        for (int r = 0; r < 4; ++r) {
            int o = row0 + lq * 4 + r;
            __builtin_nontemporal_store(acc[j][r] + bias,
                                        out + (size_t)o * OUT_FEAT + col);
        }
    }
}

extern "C" void kernel_launch(void* const* d_in, const int* in_sizes, int n_in,
                              void* d_out, int out_size, void* d_ws, size_t ws_size,
                              hipStream_t stream) {
    const float* h_s = (const float*)d_in[0];
    const float* h_d = (const float*)d_in[1];
    const int*   src = (const int*)d_in[2];
    const int*   dst = (const int*)d_in[3];
    const float* W   = (const float*)d_in[4];
    const float* b   = (const float*)d_in[5];
    float* out = (float*)d_out;

    // workspace layout (~32.3 MB), all 16-B aligned:
    //   deg    int[50000]            @ 0          (200,000 B)
    //   permu  ushort[50000*64]      @ 200,000    (6,400,000 B)
    //   hsb    ushort[50000*128]     @ 6,600,000  (12,800,000 B)
    //   hdb    ushort[50000*128]     @ 19,400,000 (12,800,000 B)
    //   wfrag  ushort[32768]         @ 32,200,000 (65,536 B)
    char* ws = (char*)d_ws;
    int*    deg    = (int*)ws;
    ushort* permu  = (ushort*)(ws + 200000);
    ushort* hsb    = (ushort*)(ws + 6600000);
    ushort* hdb    = (ushort*)(ws + 19400000);
    ushort* wfrag  = (ushort*)(ws + 32200000);

    hipMemsetAsync(deg, 0, N_DST * sizeof(int), stream);

    fill_cvt_kernel<<<K1_GRID, 256, 0, stream>>>(
        h_s, h_d, W, src, dst, deg, permu, hsb, hdb, wfrag);
    gather_gemm_kernel<<<N_DST / 16, 256, 0, stream>>>(
        hsb, deg, permu, hdb, wfrag, b, out);
}